// Round 2
// baseline (1109.206 us; speedup 1.0000x reference)
//
#include <hip/hip_runtime.h>
#include <hip/hip_bf16.h>

#define HDIM 64
#define LSEQ 1024
#define NB 64
#define NV 32000

// ---------------- Kernel 1: token transform -> k_all (fp32 in ws) ----------------
// grid 1024 x block 256 (4 waves); each wave does 16 tokens.
__global__ __launch_bounds__(256) void tok_kernel(
    const int* __restrict__ seq, const float* __restrict__ embed,
    const float* __restrict__ W1, const float* __restrict__ b1,
    const float* __restrict__ W2, const float* __restrict__ b2,
    const float* __restrict__ gamma, const float* __restrict__ beta,
    const float* __restrict__ kpW, float* __restrict__ kall)
{
  __shared__ float hbuf[4][64];
  __shared__ float y1buf[4][128];
  __shared__ float hnbuf[4][64];
  const int w = threadIdx.x >> 6, lane = threadIdx.x & 63;
  const float2* W1f2 = (const float2*)W1;   // pairs: W1[j][2*lane], W1[j][2*lane+1]
  const float2* b1f2 = (const float2*)b1;

  const float2 bb = b1f2[lane];
  const float gam = gamma[lane], bet = beta[lane], b2l = b2[lane];

  for (int tt = 0; tt < 16; ++tt) {
    const int tok = (blockIdx.x * 4 + w) * 16 + tt;
    const int row = seq[tok];
    const float h = embed[(size_t)row * HDIM + lane];
    hbuf[w][lane] = h;
    __syncthreads();

    // layer 1: y1[c] = relu(b1[c] + sum_j h[j]*W1[j][c]); lane owns c=2*lane, 2*lane+1
    float acc0 = bb.x, acc1 = bb.y;
    #pragma unroll
    for (int j = 0; j < 64; ++j) {
      const float hj = hbuf[w][j];
      const float2 ww = W1f2[j * 64 + lane];
      acc0 = fmaf(hj, ww.x, acc0);
      acc1 = fmaf(hj, ww.y, acc1);
    }
    y1buf[w][2 * lane]     = fmaxf(acc0, 0.f);
    y1buf[w][2 * lane + 1] = fmaxf(acc1, 0.f);
    __syncthreads();

    // layer 2 + residual: x[i] = h[i] + b2[i] + sum_c y1[c]*W2[c][i]; lane owns i
    float x = h + b2l;
    #pragma unroll
    for (int c = 0; c < 128; ++c)
      x = fmaf(y1buf[w][c], W2[c * 64 + lane], x);

    // layernorm over H (butterfly reductions -> bitwise-identical across lanes)
    float s1 = x, s2 = x * x;
    #pragma unroll
    for (int m = 1; m < 64; m <<= 1) { s1 += __shfl_xor(s1, m); s2 += __shfl_xor(s2, m); }
    const float mu  = s1 * (1.f / 64.f);
    const float var = s2 * (1.f / 64.f) - mu * mu;
    const float hn  = (x - mu) * rsqrtf(var + 1e-5f) * gam + bet;
    hnbuf[w][lane] = hn;
    __syncthreads();

    // k = hn @ kpW; lane owns output i
    float k = 0.f;
    #pragma unroll
    for (int j = 0; j < 64; ++j)
      k = fmaf(hnbuf[w][j], kpW[j * 64 + lane], k);
    kall[(size_t)tok * HDIM + lane] = k;
    __syncthreads();
  }
}

// ---------------- Kernel 2: sequential gated delta scan ----------------
// grid 64 (one block=wave per batch); lane i holds M row i in registers.
__global__ __launch_bounds__(64) void scan_kernel(const float* __restrict__ kall,
                                                  float* __restrict__ readv)
{
  __shared__ __align__(16) float sk[2][64];
  const int b = blockIdx.x, lane = threadIdx.x;
  const float* kb = kall + (size_t)b * LSEQ * HDIM;

  float M[64];
  #pragma unroll
  for (int j = 0; j < 64; ++j) M[j] = 0.f;

  float kv = kb[lane];          // k[0][lane]
  sk[0][lane] = kv;

  for (int t = 0; t < LSEQ - 1; ++t) {
    __syncthreads();                              // sk[t&1] visible
    const float kvn = kb[(t + 1) * HDIM + lane];  // prefetch next k (t+1 <= 1023)

    // broadcast-load full k vector from LDS into registers
    float kr[64];
    const float4* p4 = (const float4*)sk[t & 1];
    #pragma unroll
    for (int jj = 0; jj < 16; ++jj) {
      const float4 v = p4[jj];
      kr[4*jj+0] = v.x; kr[4*jj+1] = v.y; kr[4*jj+2] = v.z; kr[4*jj+3] = v.w;
    }

    // dot = M_row . k  ;  nk2 = |k|^2 (redundant per-lane, bitwise-identical)
    float d0=0,d1=0,d2=0,d3=0,n0=0,n1=0,n2=0,n3=0;
    #pragma unroll
    for (int j = 0; j < 64; j += 4) {
      d0 = fmaf(M[j+0], kr[j+0], d0); n0 = fmaf(kr[j+0], kr[j+0], n0);
      d1 = fmaf(M[j+1], kr[j+1], d1); n1 = fmaf(kr[j+1], kr[j+1], n1);
      d2 = fmaf(M[j+2], kr[j+2], d2); n2 = fmaf(kr[j+2], kr[j+2], n2);
      d3 = fmaf(M[j+3], kr[j+3], d3); n3 = fmaf(kr[j+3], kr[j+3], n3);
    }
    const float dot = (d0 + d1) + (d2 + d3);
    const float nk2 = (n0 + n1) + (n2 + n3);
    const float nk  = sqrtf(nk2);
    const float inv = 1.f / fmaxf(nk, 1e-12f);
    const float vp  = dot * inv;         // (M kn)[lane]
    const float err = kv - vp;

    float ne2 = err * err;
    #pragma unroll
    for (int m = 1; m < 64; m <<= 1) ne2 += __shfl_xor(ne2, m);

    const float coef = (sqrtf(ne2) >= 0.4f * nk) ? err * inv : 0.f;
    #pragma unroll
    for (int j = 0; j < 64; ++j) M[j] = fmaf(coef, kr[j], M[j]);

    sk[(t + 1) & 1][lane] = kvn;   // stage next k
    kv = kvn;
  }

  __syncthreads();
  // read = M @ q, q = k[1023] sits in sk[(LSEQ-1)&1]
  {
    float kr[64];
    const float4* p4 = (const float4*)sk[(LSEQ - 1) & 1];
    #pragma unroll
    for (int jj = 0; jj < 16; ++jj) {
      const float4 v = p4[jj];
      kr[4*jj+0] = v.x; kr[4*jj+1] = v.y; kr[4*jj+2] = v.z; kr[4*jj+3] = v.w;
    }
    float d0=0,d1=0,d2=0,d3=0;
    #pragma unroll
    for (int j = 0; j < 64; j += 4) {
      d0 = fmaf(M[j+0], kr[j+0], d0); d1 = fmaf(M[j+1], kr[j+1], d1);
      d2 = fmaf(M[j+2], kr[j+2], d2); d3 = fmaf(M[j+3], kr[j+3], d3);
    }
    readv[b * HDIM + lane] = (d0 + d1) + (d2 + d3);
  }
}

// ---------------- Kernel 3: r2^T = (read @ rpW + rpb)^T  (tiny) ----------------
__global__ __launch_bounds__(256) void rproj_kernel(const float* __restrict__ readv,
    const float* __restrict__ rpW, const float* __restrict__ rpb, float* __restrict__ r2T)
{
  const int i = threadIdx.x & 63;   // output feature
  const int bq = threadIdx.x >> 6;
  for (int bb = 0; bb < 16; ++bb) {
    const int b = bb * 4 + bq;
    float acc = rpb[i];
    #pragma unroll
    for (int j = 0; j < 64; ++j)
      acc = fmaf(readv[b * 64 + j], rpW[j * 64 + i], acc);
    r2T[i * 64 + b] = acc;   // transposed: [feature][batch]
  }
}

// ---------------- Kernel 4: out[b][v] = sum_k r2[b][k]*outW[k][v] + outb[v] ----------------
// grid 125 x 256: one v per thread, 64 batch accumulators in registers,
// r2T reads are wave-uniform -> scalar loads (SGPR operands).
__global__ __launch_bounds__(256) void out_kernel(const float* __restrict__ r2T,
    const float* __restrict__ outW, const float* __restrict__ outb,
    float* __restrict__ out)
{
  const int v = blockIdx.x * 256 + threadIdx.x;
  float acc[64];
  #pragma unroll
  for (int b = 0; b < 64; ++b) acc[b] = 0.f;
  for (int k = 0; k < 64; ++k) {
    const float w = outW[(size_t)k * NV + v];
    #pragma unroll
    for (int b = 0; b < 64; ++b)
      acc[b] = fmaf(r2T[k * 64 + b], w, acc[b]);
  }
  const float ob = outb[v];
  #pragma unroll
  for (int b = 0; b < 64; ++b)
    out[(size_t)b * NV + v] = acc[b] + ob;
}

extern "C" void kernel_launch(void* const* d_in, const int* in_sizes, int n_in,
                              void* d_out, int out_size, void* d_ws, size_t ws_size,
                              hipStream_t stream)
{
  const int*   seq   = (const int*)d_in[0];
  const float* embed = (const float*)d_in[1];
  const float* W1    = (const float*)d_in[2];
  const float* b1    = (const float*)d_in[3];
  const float* W2    = (const float*)d_in[4];
  const float* b2    = (const float*)d_in[5];
  const float* gam   = (const float*)d_in[6];
  const float* bet   = (const float*)d_in[7];
  const float* kpW   = (const float*)d_in[8];
  const float* rpW   = (const float*)d_in[9];
  const float* rpb   = (const float*)d_in[10];
  const float* outW  = (const float*)d_in[11];
  const float* outb  = (const float*)d_in[12];
  float* out = (float*)d_out;

  float* ws    = (float*)d_ws;
  float* kall  = ws;                                   // 64*1024*64 fp32 = 16 MB
  float* readv = ws + (size_t)NB * LSEQ * HDIM;        // 64*64
  float* r2T   = readv + NB * HDIM;                    // 64*64

  hipLaunchKernelGGL(tok_kernel, dim3(1024), dim3(256), 0, stream,
                     seq, embed, W1, b1, W2, b2, gam, bet, kpW, kall);
  hipLaunchKernelGGL(scan_kernel, dim3(NB), dim3(64), 0, stream, kall, readv);
  hipLaunchKernelGGL(rproj_kernel, dim3(1), dim3(256), 0, stream, readv, rpW, rpb, r2T);
  hipLaunchKernelGGL(out_kernel, dim3(NV / 256), dim3(256), 0, stream, r2T, outW, outb, out);
}

// Round 3
// 865.166 us; speedup vs baseline: 1.2821x; 1.2821x over previous
//
#include <hip/hip_runtime.h>
#include <hip/hip_bf16.h>

#define HDIM 64
#define LSEQ 1024
#define NB 64
#define NV 32000
#define CC 32      // chunk length
#define NCH 32     // chunks per sequence

// ---------- DPP cross-lane sum (pure VALU, stays off the lgkm FIFO) ----------
template<int CTRL>
__device__ __forceinline__ float dpp_red(float x) {
  int y = __builtin_amdgcn_update_dpp(0, __float_as_int(x), CTRL, 0xF, 0xF, true);
  return x + __int_as_float(y);
}
// full 64-lane sum, result uniform in all lanes
__device__ __forceinline__ float wave_sum(float x) {
  x = dpp_red<0xB1>(x);    // quad_perm(1,0,3,2)  : xor 1
  x = dpp_red<0x4E>(x);    // quad_perm(2,3,0,1)  : xor 2
  x = dpp_red<0x141>(x);   // row_half_mirror     : xor 7 -> sum of 8
  x = dpp_red<0x140>(x);   // row_mirror          : xor 15 -> sum of 16
  float a = __int_as_float(__builtin_amdgcn_readlane(__float_as_int(x), 0));
  float b = __int_as_float(__builtin_amdgcn_readlane(__float_as_int(x), 16));
  float c = __int_as_float(__builtin_amdgcn_readlane(__float_as_int(x), 32));
  float d = __int_as_float(__builtin_amdgcn_readlane(__float_as_int(x), 48));
  return (a + b) + (c + d);
}

// ---------- Kernel 0: transpose W1 (64x128 -> 128x64) and kpW (64x64) ----------
__global__ __launch_bounds__(256) void transpose_w(const float* __restrict__ W1,
    const float* __restrict__ kpW, float* __restrict__ W1T, float* __restrict__ kpWT)
{
  const int tid = blockIdx.x * 256 + threadIdx.x;   // grid 48 -> 12288 threads
  if (tid < 8192) { const int c = tid >> 6, j = tid & 63; W1T[tid] = W1[j * 128 + c]; }
  else { const int e = tid - 8192; const int i = e >> 6, j = e & 63; kpWT[e] = kpW[j * 64 + i]; }
}

// ---------- Kernel 1: token transform, lane = token ----------
// grid 256 x 256 threads: each lane owns one full token; weights via scalar cache.
__global__ __launch_bounds__(256) void tok2(
    const int* __restrict__ seq, const float* __restrict__ embed,
    const float* __restrict__ W1T, const float* __restrict__ b1,
    const float* __restrict__ W2, const float* __restrict__ b2,
    const float* __restrict__ gamma, const float* __restrict__ beta,
    const float* __restrict__ kpWT, float* __restrict__ kall,
    float* __restrict__ nk_all, float* __restrict__ inv_all)
{
  const int tok = blockIdx.x * 256 + threadIdx.x;
  const int row = seq[tok];
  float h[64], x[64];
  const float4* ep = (const float4*)(embed + (size_t)row * HDIM);
  #pragma unroll
  for (int q = 0; q < 16; ++q) {
    const float4 v = ep[q];
    h[4*q] = v.x; h[4*q+1] = v.y; h[4*q+2] = v.z; h[4*q+3] = v.w;
  }
  #pragma unroll
  for (int j = 0; j < 64; ++j) x[j] = h[j] + b2[j];     // b2: uniform s_load

  for (int c = 0; c < 128; ++c) {                        // FF layer1+layer2 streamed
    const float* w1r = W1T + c * 64;                     // uniform row -> s_load
    float a0 = 0.f, a1 = 0.f, a2 = 0.f, a3 = 0.f;
    #pragma unroll
    for (int j = 0; j < 64; j += 4) {
      a0 = fmaf(h[j],   w1r[j],   a0);
      a1 = fmaf(h[j+1], w1r[j+1], a1);
      a2 = fmaf(h[j+2], w1r[j+2], a2);
      a3 = fmaf(h[j+3], w1r[j+3], a3);
    }
    const float y = fmaxf(b1[c] + ((a0 + a1) + (a2 + a3)), 0.f);
    const float* w2r = W2 + c * 64;                      // uniform row -> s_load
    #pragma unroll
    for (int j = 0; j < 64; ++j) x[j] = fmaf(y, w2r[j], x[j]);
  }

  // layernorm (per-lane, no cross-lane traffic)
  float s0=0.f,s1=0.f,s2=0.f,s3=0.f,q0=0.f,q1=0.f,q2=0.f,q3=0.f;
  #pragma unroll
  for (int j = 0; j < 64; j += 4) {
    s0 += x[j]; s1 += x[j+1]; s2 += x[j+2]; s3 += x[j+3];
    q0 = fmaf(x[j],   x[j],   q0); q1 = fmaf(x[j+1], x[j+1], q1);
    q2 = fmaf(x[j+2], x[j+2], q2); q3 = fmaf(x[j+3], x[j+3], q3);
  }
  const float mu  = ((s0+s1)+(s2+s3)) * (1.f/64.f);
  const float var = ((q0+q1)+(q2+q3)) * (1.f/64.f) - mu * mu;
  const float rs  = rsqrtf(var + 1e-5f);
  #pragma unroll
  for (int j = 0; j < 64; ++j) h[j] = (x[j] - mu) * rs * gamma[j] + beta[j];

  // k projection (runtime i loop keeps code small); raw k to global + norms
  float nk2 = 0.f;
  float* kout = kall + (size_t)tok * HDIM;
  for (int i = 0; i < 64; ++i) {
    const float* kr = kpWT + i * 64;                     // uniform row -> s_load
    float c0=0.f,c1=0.f,c2=0.f,c3=0.f;
    #pragma unroll
    for (int j = 0; j < 64; j += 4) {
      c0 = fmaf(h[j],   kr[j],   c0);
      c1 = fmaf(h[j+1], kr[j+1], c1);
      c2 = fmaf(h[j+2], kr[j+2], c2);
      c3 = fmaf(h[j+3], kr[j+3], c3);
    }
    const float ki = (c0 + c1) + (c2 + c3);
    nk2 = fmaf(ki, ki, nk2);
    kout[i] = ki;
  }
  const float nk  = sqrtf(nk2);
  const float inv = 1.f / fmaxf(nk, 1e-12f);
  nk_all[tok] = nk; inv_all[tok] = inv;
}

// ---------- Kernel 2: per-chunk normalized Gram  G[b][ch][t][s] = kn_t . kn_s ----------
__global__ __launch_bounds__(256) void gram_kernel(const float* __restrict__ kall,
    const float* __restrict__ inv_all, float* __restrict__ G)
{
  const int b = blockIdx.x >> 5, ch = blockIdx.x & 31;
  __shared__ float kS[CC][65];     // +1 pad: kS[t][j] bank = (t+j)%32
  __shared__ float invS[CC];
  const int tid = threadIdx.x;
  const float* src = kall + ((size_t)b * LSEQ + ch * CC) * HDIM;
  #pragma unroll
  for (int q = 0; q < 8; ++q) {
    const int e = q * 256 + tid;   // 2048 elements
    kS[e >> 6][e & 63] = src[e];
  }
  if (tid < CC) invS[tid] = inv_all[b * LSEQ + ch * CC + tid];
  __syncthreads();
  const int t = tid >> 3, s0 = (tid & 7) * 4;
  float g0=0.f,g1=0.f,g2=0.f,g3=0.f;
  #pragma unroll
  for (int j = 0; j < 64; ++j) {
    const float kt = kS[t][j];
    g0 = fmaf(kt, kS[s0  ][j], g0);
    g1 = fmaf(kt, kS[s0+1][j], g1);
    g2 = fmaf(kt, kS[s0+2][j], g2);
    g3 = fmaf(kt, kS[s0+3][j], g3);
  }
  const float it = invS[t];
  float4 o;
  o.x = g0 * it * invS[s0];   o.y = g1 * it * invS[s0+1];
  o.z = g2 * it * invS[s0+2]; o.w = g3 * it * invS[s0+3];
  ((float4*)(G + (size_t)blockIdx.x * (CC * CC)))[tid] = o;
}

// ---------- Kernel 3: chunked gated delta scan ----------
// grid 64 (one block per batch) x 256 threads (4 waves).
// thread (w,lane) holds M[lane][16w..16w+15]; wave 0 runs the serial inner core.
__global__ __launch_bounds__(256) void scan2(
    const float* __restrict__ kall, const float* __restrict__ nk_all,
    const float* __restrict__ inv_all, const float* __restrict__ G,
    float* __restrict__ readv)
{
  const int b = blockIdx.x;
  const int w = threadIdx.x >> 6, lane = threadIdx.x & 63;
  __shared__ float pbS[CC][4][64];   // base partials [t][w][lane]
  __shared__ float rS[CC][64];       // residual r_t = k_t - M0 kn_t
  __shared__ float cstS[CC][64];     // c'_s = gate*err*inv  (normalized coef)

  float M[16];
  #pragma unroll
  for (int jj = 0; jj < 16; ++jj) M[jj] = 0.f;

  const float* kb  = kall    + (size_t)b * LSEQ * HDIM;
  const float* nkb = nk_all  + b * LSEQ;
  const float* ivb = inv_all + b * LSEQ;
  const float* Gb  = G + (size_t)b * NCH * (CC * CC);

  for (int ch = 0; ch < NCH; ++ch) {
    const int T = ch * CC;
    // ---- A2: base partials (raw dot; scaled by inv at combine) ----
    #pragma unroll 4
    for (int t = 0; t < CC; ++t) {
      const float* kr = kb + (size_t)(T + t) * HDIM + w * 16;  // wave-uniform -> s_load
      float p0=0.f,p1=0.f,p2=0.f,p3=0.f;
      #pragma unroll
      for (int jj = 0; jj < 16; jj += 4) {
        p0 = fmaf(M[jj],   kr[jj],   p0);
        p1 = fmaf(M[jj+1], kr[jj+1], p1);
        p2 = fmaf(M[jj+2], kr[jj+2], p2);
        p3 = fmaf(M[jj+3], kr[jj+3], p3);
      }
      pbS[t][w][lane] = (p0 + p1) + (p2 + p3);
    }
    __syncthreads();
    // ---- A3: combine -> r_t ----
    #pragma unroll
    for (int q = 0; q < 8; ++q) {
      const int t = w * 8 + q;
      const float base = ((pbS[t][0][lane] + pbS[t][1][lane]) +
                          (pbS[t][2][lane] + pbS[t][3][lane])) * ivb[T + t];
      rS[t][lane] = kb[(size_t)(T + t) * HDIM + lane] - base;
    }
    __syncthreads();
    // ---- B: serial inner core (wave 0 only) ----
    if (w == 0) {
      float acc[CC];
      #pragma unroll
      for (int t = 0; t < CC; ++t) acc[t] = rS[t][lane];
      const float* Gc = Gb + ch * (CC * CC);
      const bool lastch = (ch == NCH - 1);
      #pragma unroll
      for (int t = 0; t < CC; ++t) {
        // prefetch G row t (uniform -> s_load), issued before the reduction chain
        float gr[CC];
        #pragma unroll
        for (int u = t + 1; u < CC; ++u) gr[u] = Gc[t * CC + u];
        const float err = acc[t];
        const float ne2 = wave_sum(err * err);
        const float nk  = nkb[T + t];
        bool gate = (sqrtf(ne2) >= 0.4f * nk);
        if (lastch && t == CC - 1) gate = false;   // token 1023 excluded from scan
        const float c = gate ? err : 0.f;
        cstS[t][lane] = c * ivb[T + t];
        #pragma unroll
        for (int u = t + 1; u < CC; ++u)
          acc[u] = fmaf(-gr[u], c, acc[u]);
      }
    }
    __syncthreads();
    // ---- C: rank-CC update of M (fused with next chunk's A2; no barrier needed) ----
    #pragma unroll 4
    for (int s = 0; s < CC; ++s) {
      const float cs = cstS[s][lane];
      const float* kr = kb + (size_t)(T + s) * HDIM + w * 16;  // uniform -> s_load
      #pragma unroll
      for (int jj = 0; jj < 16; ++jj)
        M[jj] = fmaf(cs, kr[jj], M[jj]);
    }
  }

  // ---- final read = M . q, q = raw k[1023] ----
  {
    const float* qr = kb + (size_t)1023 * HDIM + w * 16;
    float p0=0.f,p1=0.f,p2=0.f,p3=0.f;
    #pragma unroll
    for (int jj = 0; jj < 16; jj += 4) {
      p0 = fmaf(M[jj],   qr[jj],   p0);
      p1 = fmaf(M[jj+1], qr[jj+1], p1);
      p2 = fmaf(M[jj+2], qr[jj+2], p2);
      p3 = fmaf(M[jj+3], qr[jj+3], p3);
    }
    pbS[0][w][lane] = (p0 + p1) + (p2 + p3);
  }
  __syncthreads();
  if (w == 0)
    readv[b * HDIM + lane] = (pbS[0][0][lane] + pbS[0][1][lane]) +
                             (pbS[0][2][lane] + pbS[0][3][lane]);
}

// ---------- Kernel 4: r2^T = (read @ rpW + rpb)^T ----------
__global__ __launch_bounds__(256) void rproj_kernel(const float* __restrict__ readv,
    const float* __restrict__ rpW, const float* __restrict__ rpb, float* __restrict__ r2T)
{
  const int i = threadIdx.x & 63;
  const int bq = threadIdx.x >> 6;
  for (int bb = 0; bb < 16; ++bb) {
    const int b = bb * 4 + bq;
    float acc = rpb[i];
    #pragma unroll
    for (int j = 0; j < 64; ++j)
      acc = fmaf(readv[b * 64 + j], rpW[j * 64 + i], acc);
    r2T[i * 64 + b] = acc;
  }
}

// ---------- Kernel 5: out = r2 @ outW + outb ----------
__global__ __launch_bounds__(256) void out_kernel(const float* __restrict__ r2T,
    const float* __restrict__ outW, const float* __restrict__ outb,
    float* __restrict__ out)
{
  const int v = blockIdx.x * 256 + threadIdx.x;
  float acc[64];
  #pragma unroll
  for (int b = 0; b < 64; ++b) acc[b] = 0.f;
  for (int k = 0; k < 64; ++k) {
    const float wv = outW[(size_t)k * NV + v];
    #pragma unroll
    for (int b = 0; b < 64; ++b)
      acc[b] = fmaf(r2T[k * 64 + b], wv, acc[b]);
  }
  const float ob = outb[v];
  #pragma unroll
  for (int b = 0; b < 64; ++b)
    out[(size_t)b * NV + v] = acc[b] + ob;
}

extern "C" void kernel_launch(void* const* d_in, const int* in_sizes, int n_in,
                              void* d_out, int out_size, void* d_ws, size_t ws_size,
                              hipStream_t stream)
{
  const int*   seq   = (const int*)d_in[0];
  const float* embed = (const float*)d_in[1];
  const float* W1    = (const float*)d_in[2];
  const float* b1    = (const float*)d_in[3];
  const float* W2    = (const float*)d_in[4];
  const float* b2    = (const float*)d_in[5];
  const float* gam   = (const float*)d_in[6];
  const float* bet   = (const float*)d_in[7];
  const float* kpW   = (const float*)d_in[8];
  const float* rpW   = (const float*)d_in[9];
  const float* rpb   = (const float*)d_in[10];
  const float* outW  = (const float*)d_in[11];
  const float* outb  = (const float*)d_in[12];
  float* out = (float*)d_out;

  float* ws = (float*)d_ws;
  float* kall  = ws;                                    // 4,194,304 f
  float* G     = kall  + (size_t)NB * LSEQ * HDIM;      // 2,097,152 f
  float* nk    = G     + (size_t)NB * NCH * CC * CC;    //    65,536 f
  float* inv   = nk    + NB * LSEQ;                     //    65,536 f
  float* readv = inv   + NB * LSEQ;                     //     4,096 f
  float* r2T   = readv + NB * HDIM;                     //     4,096 f
  float* W1T   = r2T   + NB * HDIM;                     //     8,192 f
  float* kpWT  = W1T   + 8192;                          //     4,096 f

  hipLaunchKernelGGL(transpose_w, dim3(48), dim3(256), 0, stream, W1, kpW, W1T, kpWT);
  hipLaunchKernelGGL(tok2, dim3(256), dim3(256), 0, stream,
                     seq, embed, W1T, b1, W2, b2, gam, bet, kpWT, kall, nk, inv);
  hipLaunchKernelGGL(gram_kernel, dim3(NB * NCH), dim3(256), 0, stream, kall, inv, G);
  hipLaunchKernelGGL(scan2, dim3(NB), dim3(256), 0, stream, kall, nk, inv, G, readv);
  hipLaunchKernelGGL(rproj_kernel, dim3(1), dim3(256), 0, stream, readv, rpW, rpb, r2T);
  hipLaunchKernelGGL(out_kernel, dim3(NV / 256), dim3(256), 0, stream, r2T, outW, outb, out);
}

// Round 4
// 577.422 us; speedup vs baseline: 1.9210x; 1.4983x over previous
//
#include <hip/hip_runtime.h>
#include <hip/hip_bf16.h>

#define HDIM 64
#define LSEQ 1024
#define NB 64
#define NV 32000
#define CC 32      // chunk length
#define NCH 32     // chunks per sequence
#define NT (NB * LSEQ)   // total tokens = kallT row stride

// ---------- DPP cross-lane sum (pure VALU) ----------
template<int CTRL>
__device__ __forceinline__ float dpp_red(float x) {
  int y = __builtin_amdgcn_update_dpp(0, __float_as_int(x), CTRL, 0xF, 0xF, true);
  return x + __int_as_float(y);
}
__device__ __forceinline__ float wave_sum(float x) {
  x = dpp_red<0xB1>(x);    // xor 1
  x = dpp_red<0x4E>(x);    // xor 2
  x = dpp_red<0x141>(x);   // row_half_mirror -> sum of 8
  x = dpp_red<0x140>(x);   // row_mirror      -> sum of 16
  float a = __int_as_float(__builtin_amdgcn_readlane(__float_as_int(x), 0));
  float b = __int_as_float(__builtin_amdgcn_readlane(__float_as_int(x), 16));
  float c = __int_as_float(__builtin_amdgcn_readlane(__float_as_int(x), 32));
  float d = __int_as_float(__builtin_amdgcn_readlane(__float_as_int(x), 48));
  return (a + b) + (c + d);
}

// ---------- Kernel 0: transpose W1 (64x128 -> 128x64) and kpW (64x64) ----------
__global__ __launch_bounds__(256) void transpose_w(const float* __restrict__ W1,
    const float* __restrict__ kpW, float* __restrict__ W1T, float* __restrict__ kpWT)
{
  const int tid = blockIdx.x * 256 + threadIdx.x;   // grid 48 -> 12288 threads
  if (tid < 8192) { const int c = tid >> 6, j = tid & 63; W1T[tid] = W1[j * 128 + c]; }
  else { const int e = tid - 8192; const int i = e >> 6, j = e & 63; kpWT[e] = kpW[j * 64 + i]; }
}

// ---------- Kernel 1: token transform, lane = token; weights in LDS ----------
// grid 256 x 256 threads; writes k TRANSPOSED: kallT[i][tok] (coalesced stores).
__global__ __launch_bounds__(256, 1) void tok3(
    const int* __restrict__ seq, const float* __restrict__ embed,
    const float* __restrict__ W1T, const float* __restrict__ b1,
    const float* __restrict__ W2, const float* __restrict__ b2,
    const float* __restrict__ gamma, const float* __restrict__ beta,
    const float* __restrict__ kpWT, float* __restrict__ kallT,
    float* __restrict__ nk_all, float* __restrict__ inv_all)
{
  __shared__ float w1s[128 * 64];   // 32 KB
  __shared__ float w2s[128 * 64];   // 32 KB
  const int tid = threadIdx.x;
  {
    float4* l1 = (float4*)w1s; const float4* g1 = (const float4*)W1T;
    #pragma unroll
    for (int q = 0; q < 8; ++q) l1[q * 256 + tid] = g1[q * 256 + tid];
    float4* l2 = (float4*)w2s; const float4* g2 = (const float4*)W2;
    #pragma unroll
    for (int q = 0; q < 8; ++q) l2[q * 256 + tid] = g2[q * 256 + tid];
  }
  __syncthreads();

  const int tok = blockIdx.x * 256 + tid;
  const int row = seq[tok];
  float h[64], x[64];
  const float4* ep = (const float4*)(embed + (size_t)row * HDIM);
  #pragma unroll
  for (int q = 0; q < 16; ++q) {
    const float4 v = ep[q];
    h[4*q] = v.x; h[4*q+1] = v.y; h[4*q+2] = v.z; h[4*q+3] = v.w;
  }
  #pragma unroll
  for (int j = 0; j < 64; ++j) x[j] = h[j] + b2[j];

  for (int c = 0; c < 128; ++c) {
    const float* w1r = &w1s[c * 64];        // broadcast ds_read rows
    float a0 = 0.f, a1 = 0.f, a2 = 0.f, a3 = 0.f;
    #pragma unroll
    for (int j = 0; j < 64; j += 4) {
      a0 = fmaf(h[j],   w1r[j],   a0);
      a1 = fmaf(h[j+1], w1r[j+1], a1);
      a2 = fmaf(h[j+2], w1r[j+2], a2);
      a3 = fmaf(h[j+3], w1r[j+3], a3);
    }
    const float y = fmaxf(b1[c] + ((a0 + a1) + (a2 + a3)), 0.f);
    const float* w2r = &w2s[c * 64];
    #pragma unroll
    for (int j = 0; j < 64; ++j) x[j] = fmaf(y, w2r[j], x[j]);
  }

  // layernorm (per-lane)
  float s0=0.f,s1=0.f,s2=0.f,s3=0.f,q0=0.f,q1=0.f,q2=0.f,q3=0.f;
  #pragma unroll
  for (int j = 0; j < 64; j += 4) {
    s0 += x[j]; s1 += x[j+1]; s2 += x[j+2]; s3 += x[j+3];
    q0 = fmaf(x[j],   x[j],   q0); q1 = fmaf(x[j+1], x[j+1], q1);
    q2 = fmaf(x[j+2], x[j+2], q2); q3 = fmaf(x[j+3], x[j+3], q3);
  }
  const float mu  = ((s0+s1)+(s2+s3)) * (1.f/64.f);
  const float var = ((q0+q1)+(q2+q3)) * (1.f/64.f) - mu * mu;
  const float rs  = rsqrtf(var + 1e-5f);
  #pragma unroll
  for (int j = 0; j < 64; ++j) h[j] = (x[j] - mu) * rs * gamma[j] + beta[j];

  // k projection; store transposed (coalesced across lanes)
  float nk2 = 0.f;
  for (int i = 0; i < 64; ++i) {
    const float* kr = kpWT + i * 64;        // uniform -> s_load
    float c0=0.f,c1=0.f,c2=0.f,c3=0.f;
    #pragma unroll
    for (int j = 0; j < 64; j += 4) {
      c0 = fmaf(h[j],   kr[j],   c0);
      c1 = fmaf(h[j+1], kr[j+1], c1);
      c2 = fmaf(h[j+2], kr[j+2], c2);
      c3 = fmaf(h[j+3], kr[j+3], c3);
    }
    const float ki = (c0 + c1) + (c2 + c3);
    nk2 = fmaf(ki, ki, nk2);
    kallT[(size_t)i * NT + tok] = ki;
  }
  const float nk  = sqrtf(nk2);
  nk_all[tok]  = nk;
  inv_all[tok] = 1.f / fmaxf(nk, 1e-12f);
}

// ---------- Kernel 2: per-chunk normalized Gram from kallT ----------
__global__ __launch_bounds__(256) void gram_kernel(const float* __restrict__ kallT,
    const float* __restrict__ inv_all, float* __restrict__ G)
{
  const int b = blockIdx.x >> 5, ch = blockIdx.x & 31;
  __shared__ float kS[CC * 65];
  __shared__ float invS[CC];
  const int tid = threadIdx.x;
  const int gbase = b * LSEQ + ch * CC;
  #pragma unroll
  for (int q = 0; q < 8; ++q) {
    const int e = q * 256 + tid;            // 2048 elements
    const int j = e >> 5, t = e & 31;
    kS[t * 65 + j] = kallT[(size_t)j * NT + gbase + t];
  }
  if (tid < CC) invS[tid] = inv_all[gbase + tid];
  __syncthreads();
  const int t = tid >> 3, s0 = (tid & 7) * 4;
  float g0=0.f,g1=0.f,g2=0.f,g3=0.f;
  #pragma unroll
  for (int j = 0; j < 64; ++j) {
    const float kt = kS[t * 65 + j];
    g0 = fmaf(kt, kS[(s0  ) * 65 + j], g0);
    g1 = fmaf(kt, kS[(s0+1) * 65 + j], g1);
    g2 = fmaf(kt, kS[(s0+2) * 65 + j], g2);
    g3 = fmaf(kt, kS[(s0+3) * 65 + j], g3);
  }
  const float it = invS[t];
  float4 o;
  o.x = g0 * it * invS[s0];   o.y = g1 * it * invS[s0+1];
  o.z = g2 * it * invS[s0+2]; o.w = g3 * it * invS[s0+3];
  ((float4*)(G + (size_t)blockIdx.x * (CC * CC)))[tid] = o;
}

// ---------- Kernel 3: chunked gated delta scan, all-LDS working set ----------
__global__ __launch_bounds__(256, 1) void scan3(
    const float* __restrict__ kallT, const float* __restrict__ nk_all,
    const float* __restrict__ inv_all, const float* __restrict__ G,
    float* __restrict__ readv)
{
  __shared__ float kS[CC * 64];      // raw k rows [t][j]          8 KB
  __shared__ float GS[CC * CC];      // normalized Gram [t][s]     4 KB
  __shared__ float rS[CC * 64];      // residuals                  8 KB
  __shared__ float cstS[CC * 64];    // gated raw err              8 KB
  __shared__ float pbS[CC * 4 * 64]; // base partials [t][w][lane] 32 KB
  __shared__ float thrS[CC];
  __shared__ float invS[CC];

  const int b = blockIdx.x;
  const int tid = threadIdx.x;
  const int w = tid >> 6, lane = tid & 63;
  const int sj = tid >> 2, st0 = (tid & 3) * 8;

  float M[16];
  #pragma unroll
  for (int jj = 0; jj < 16; ++jj) M[jj] = 0.f;

  const float* Gb = G + (size_t)b * NCH * (CC * CC);

  for (int ch = 0; ch < NCH; ++ch) {
    const int T = ch * CC;
    // ---- stage: k chunk (from transposed layout), G, thr, inv ----
    {
      const float* src = kallT + (size_t)sj * NT + (b * LSEQ + T + st0);
      const float4 va = ((const float4*)src)[0];
      const float4 vb = ((const float4*)src)[1];
      kS[(st0+0)*64+sj] = va.x; kS[(st0+1)*64+sj] = va.y;
      kS[(st0+2)*64+sj] = va.z; kS[(st0+3)*64+sj] = va.w;
      kS[(st0+4)*64+sj] = vb.x; kS[(st0+5)*64+sj] = vb.y;
      kS[(st0+6)*64+sj] = vb.z; kS[(st0+7)*64+sj] = vb.w;
      ((float4*)GS)[tid] = ((const float4*)(Gb + ch * (CC * CC)))[tid];
      if (tid < CC) thrS[tid] = 0.4f * nk_all[b * LSEQ + T + tid];
      else if (tid < 2 * CC) invS[tid - CC] = inv_all[b * LSEQ + T + (tid - CC)];
    }
    __syncthreads();
    // ---- A2: base partials (M . k_raw over this wave's j-slice) ----
    #pragma unroll
    for (int t = 0; t < CC; ++t) {
      const float4* k4 = (const float4*)&kS[t * 64 + w * 16];
      const float4 k0 = k4[0], k1 = k4[1], k2 = k4[2], k3 = k4[3];
      float a0=0.f,a1=0.f,a2=0.f,a3=0.f;
      a0=fmaf(M[0],k0.x,a0); a1=fmaf(M[1],k0.y,a1); a2=fmaf(M[2],k0.z,a2); a3=fmaf(M[3],k0.w,a3);
      a0=fmaf(M[4],k1.x,a0); a1=fmaf(M[5],k1.y,a1); a2=fmaf(M[6],k1.z,a2); a3=fmaf(M[7],k1.w,a3);
      a0=fmaf(M[8],k2.x,a0); a1=fmaf(M[9],k2.y,a1); a2=fmaf(M[10],k2.z,a2); a3=fmaf(M[11],k2.w,a3);
      a0=fmaf(M[12],k3.x,a0); a1=fmaf(M[13],k3.y,a1); a2=fmaf(M[14],k3.z,a2); a3=fmaf(M[15],k3.w,a3);
      pbS[(t * 4 + w) * 64 + lane] = (a0 + a1) + (a2 + a3);
    }
    __syncthreads();
    // ---- A3: combine -> residual r_t = k_t - (M k_t) * inv_t ----
    #pragma unroll
    for (int q = 0; q < 8; ++q) {
      const int t = w * 8 + q;
      const float base = ((pbS[(t*4+0)*64+lane] + pbS[(t*4+1)*64+lane]) +
                          (pbS[(t*4+2)*64+lane] + pbS[(t*4+3)*64+lane])) * invS[t];
      rS[t * 64 + lane] = kS[t * 64 + lane] - base;
    }
    __syncthreads();
    // ---- B: serial inner core (wave 0) ----
    if (w == 0) {
      float acc[CC], thrv[CC];
      #pragma unroll
      for (int t = 0; t < CC; ++t) acc[t] = rS[t * 64 + lane];
      #pragma unroll
      for (int q = 0; q < 8; ++q) {
        const float4 v = ((const float4*)thrS)[q];
        thrv[4*q] = v.x; thrv[4*q+1] = v.y; thrv[4*q+2] = v.z; thrv[4*q+3] = v.w;
      }
      const bool lastch = (ch == NCH - 1);
      #pragma unroll
      for (int t = 0; t < CC; ++t) {
        const float err = acc[t];
        const float ne2 = wave_sum(err * err);
        bool gate = (sqrtf(ne2) >= thrv[t]);
        if (lastch && t == CC - 1) gate = false;   // token 1023 excluded
        const float c = gate ? err : 0.f;
        cstS[t * 64 + lane] = c;
        #pragma unroll
        for (int u = t + 1; u < CC; ++u)
          acc[u] = fmaf(-GS[t * CC + u], c, acc[u]);
      }
    }
    __syncthreads();
    // ---- C: rank-CC update of M ----
    #pragma unroll
    for (int s = 0; s < CC; ++s) {
      const float csi = cstS[s * 64 + lane] * invS[s];
      const float4* k4 = (const float4*)&kS[s * 64 + w * 16];
      const float4 k0 = k4[0], k1 = k4[1], k2 = k4[2], k3 = k4[3];
      M[0]=fmaf(csi,k0.x,M[0]);  M[1]=fmaf(csi,k0.y,M[1]);
      M[2]=fmaf(csi,k0.z,M[2]);  M[3]=fmaf(csi,k0.w,M[3]);
      M[4]=fmaf(csi,k1.x,M[4]);  M[5]=fmaf(csi,k1.y,M[5]);
      M[6]=fmaf(csi,k1.z,M[6]);  M[7]=fmaf(csi,k1.w,M[7]);
      M[8]=fmaf(csi,k2.x,M[8]);  M[9]=fmaf(csi,k2.y,M[9]);
      M[10]=fmaf(csi,k2.z,M[10]); M[11]=fmaf(csi,k2.w,M[11]);
      M[12]=fmaf(csi,k3.x,M[12]); M[13]=fmaf(csi,k3.y,M[13]);
      M[14]=fmaf(csi,k3.z,M[14]); M[15]=fmaf(csi,k3.w,M[15]);
    }
    __syncthreads();
  }

  // ---- final read = M . q, q = raw k[1023] = kS row 31 of last chunk ----
  {
    const float4* k4 = (const float4*)&kS[(CC - 1) * 64 + w * 16];
    const float4 k0 = k4[0], k1 = k4[1], k2 = k4[2], k3 = k4[3];
    float a0=0.f,a1=0.f,a2=0.f,a3=0.f;
    a0=fmaf(M[0],k0.x,a0); a1=fmaf(M[1],k0.y,a1); a2=fmaf(M[2],k0.z,a2); a3=fmaf(M[3],k0.w,a3);
    a0=fmaf(M[4],k1.x,a0); a1=fmaf(M[5],k1.y,a1); a2=fmaf(M[6],k1.z,a2); a3=fmaf(M[7],k1.w,a3);
    a0=fmaf(M[8],k2.x,a0); a1=fmaf(M[9],k2.y,a1); a2=fmaf(M[10],k2.z,a2); a3=fmaf(M[11],k2.w,a3);
    a0=fmaf(M[12],k3.x,a0); a1=fmaf(M[13],k3.y,a1); a2=fmaf(M[14],k3.z,a2); a3=fmaf(M[15],k3.w,a3);
    pbS[w * 64 + lane] = (a0 + a1) + (a2 + a3);
  }
  __syncthreads();
  if (w == 0)
    readv[b * HDIM + lane] = (pbS[0*64+lane] + pbS[1*64+lane]) +
                             (pbS[2*64+lane] + pbS[3*64+lane]);
}

// ---------- Kernel 4: r2 = read @ rpW + rpb  (grid 64 x 64) ----------
__global__ __launch_bounds__(64) void rproj_kernel(const float* __restrict__ readv,
    const float* __restrict__ rpW, const float* __restrict__ rpb, float* __restrict__ r2)
{
  const int b = blockIdx.x, i = threadIdx.x;
  const float* rv = readv + b * 64;          // uniform -> s_load
  float acc = rpb[i];
  #pragma unroll
  for (int j = 0; j < 64; ++j)
    acc = fmaf(rv[j], rpW[j * 64 + i], acc);
  r2[b * 64 + i] = acc;
}

// ---------- Kernel 5: out = r2 @ outW + outb  (grid 250 x 128) ----------
__global__ __launch_bounds__(128, 1) void out_kernel(const float* __restrict__ r2,
    const float* __restrict__ outW, const float* __restrict__ outb,
    float* __restrict__ out)
{
  const int v = blockIdx.x * 128 + threadIdx.x;
  float acc[64];
  #pragma unroll
  for (int b = 0; b < 64; ++b) acc[b] = 0.f;
  for (int k = 0; k < 64; ++k) {
    const float wv = outW[(size_t)k * NV + v];
    #pragma unroll
    for (int b = 0; b < 64; ++b)
      acc[b] = fmaf(r2[b * 64 + k], wv, acc[b]);   // r2: uniform -> s_load
  }
  const float ob = outb[v];
  #pragma unroll
  for (int b = 0; b < 64; ++b)
    out[(size_t)b * NV + v] = acc[b] + ob;
}

extern "C" void kernel_launch(void* const* d_in, const int* in_sizes, int n_in,
                              void* d_out, int out_size, void* d_ws, size_t ws_size,
                              hipStream_t stream)
{
  const int*   seq   = (const int*)d_in[0];
  const float* embed = (const float*)d_in[1];
  const float* W1    = (const float*)d_in[2];
  const float* b1    = (const float*)d_in[3];
  const float* W2    = (const float*)d_in[4];
  const float* b2    = (const float*)d_in[5];
  const float* gam   = (const float*)d_in[6];
  const float* bet   = (const float*)d_in[7];
  const float* kpW   = (const float*)d_in[8];
  const float* rpW   = (const float*)d_in[9];
  const float* rpb   = (const float*)d_in[10];
  const float* outW  = (const float*)d_in[11];
  const float* outb  = (const float*)d_in[12];
  float* out = (float*)d_out;

  float* ws = (float*)d_ws;
  float* kallT = ws;                                    // 4,194,304 f (transposed [i][tok])
  float* G     = kallT + (size_t)HDIM * NT;             // 2,097,152 f
  float* nk    = G     + (size_t)NB * NCH * CC * CC;    //    65,536 f
  float* inv   = nk    + NT;                            //    65,536 f
  float* readv = inv   + NT;                            //     4,096 f
  float* r2    = readv + NB * HDIM;                     //     4,096 f
  float* W1T   = r2    + NB * HDIM;                     //     8,192 f
  float* kpWT  = W1T   + 8192;                          //     4,096 f

  hipLaunchKernelGGL(transpose_w, dim3(48), dim3(256), 0, stream, W1, kpW, W1T, kpWT);
  hipLaunchKernelGGL(tok3, dim3(256), dim3(256), 0, stream,
                     seq, embed, W1T, b1, W2, b2, gam, bet, kpWT, kallT, nk, inv);
  hipLaunchKernelGGL(gram_kernel, dim3(NB * NCH), dim3(256), 0, stream, kallT, inv, G);
  hipLaunchKernelGGL(scan3, dim3(NB), dim3(256), 0, stream, kallT, nk, inv, G, readv);
  hipLaunchKernelGGL(rproj_kernel, dim3(NB), dim3(64), 0, stream, readv, rpW, rpb, r2);
  hipLaunchKernelGGL(out_kernel, dim3(NV / 128), dim3(128), 0, stream, r2, outW, outb, out);
}